// Round 1
// baseline (531.306 us; speedup 1.0000x reference)
//
#include <hip/hip_runtime.h>

// GGNN on MI355X.
// Pipeline: [precompute_swt -> big_mm -> gating] x2; step-2 gating fuses the
// output head. All heavy math in bf16 MFMA (16x16x32), accumulate f32.
// A (256 MB f32) is the dominant HBM stream, read once per propagate step.

typedef float  f32x4_t  __attribute__((ext_vector_type(4)));
typedef __bf16 bf16x8_t __attribute__((ext_vector_type(8)));
typedef __bf16 bf16x4_t __attribute__((ext_vector_type(4)));

#define MFMA16(a, b, c) __builtin_amdgcn_mfma_f32_16x16x32_bf16((a), (b), (c), 0, 0, 0)

static constexpr int kB  = 8;
static constexpr int kN  = 1000;
static constexpr int kD  = 64;
static constexpr int kAD = 32;
static constexpr int kNE = 4000;  // N*E

__device__ __forceinline__ float4 ld4(const float* p) {
    return *reinterpret_cast<const float4*>(p);
}

__device__ __forceinline__ bf16x8_t cvt8(float4 a, float4 b) {
    bf16x8_t r;
    r[0] = (__bf16)a.x; r[1] = (__bf16)a.y; r[2] = (__bf16)a.z; r[3] = (__bf16)a.w;
    r[4] = (__bf16)b.x; r[5] = (__bf16)b.y; r[6] = (__bf16)b.z; r[7] = (__bf16)b.w;
    return r;
}

__device__ __forceinline__ float sigm(float x) {
    x = fminf(fmaxf(x, -30.f), 30.f);
    return 1.0f / (1.0f + __expf(-x));
}

__device__ __forceinline__ float fast_tanh(float x) {
    x = fminf(fmaxf(x, -15.f), 15.f);
    const float e = __expf(-2.0f * x);
    return (1.0f - e) / (1.0f + e);
}

// ---------------------------------------------------------------------------
// SWT[(b*2+h)*64 + f][j] (bf16, j = e*1000 + jj, row stride kNE) =
//   sum_d state[b][jj][d] * W[e][f][d]   with W = (h ? W_out : W_in)
// Stored transposed so big_mm's B-fragments are contiguous 16B loads.
// grid: 1024 = 16 jt x 4 e x 2 h x 8 b, block 256 (4 waves, 16 j-rows each).
// ---------------------------------------------------------------------------
__global__ __launch_bounds__(256) void precompute_swt(
    const float* __restrict__ state,   // [8000][64]
    const float* __restrict__ W_in,    // [4][64][64]
    const float* __restrict__ W_out,
    __bf16* __restrict__ SWT)
{
    const int bx = blockIdx.x;
    const int jt = bx & 15;
    const int e  = (bx >> 4) & 3;
    const int h  = (bx >> 6) & 1;
    const int b  = bx >> 7;
    const float* W = (h ? W_out : W_in) + e * kD * kD;

    const int tid  = threadIdx.x;
    const int w    = tid >> 6;
    const int lane = tid & 63;
    const int m    = lane & 15;
    const int q    = lane >> 4;

    __shared__ __bf16 T[64][72];  // [f][j_local], +8 pad vs bank conflicts

    const int  jj    = jt * 64 + w * 16 + m;
    const bool valid = (jj < kN);
    const float* srow = state + ((size_t)b * kN + (valid ? jj : kN - 1)) * kD + q * 8;
    float4 a0 = ld4(srow),      a1 = ld4(srow + 4);
    float4 a2 = ld4(srow + 32), a3 = ld4(srow + 36);
    if (!valid) {
        a0 = make_float4(0.f, 0.f, 0.f, 0.f); a1 = a0; a2 = a0; a3 = a0;
    }
    const bf16x8_t af0 = cvt8(a0, a1);
    const bf16x8_t af1 = cvt8(a2, a3);

    #pragma unroll
    for (int c = 0; c < 4; ++c) {
        const int f = c * 16 + m;
        const float* wrow = W + f * kD + q * 8;
        const bf16x8_t bf0 = cvt8(ld4(wrow),      ld4(wrow + 4));
        const bf16x8_t bf1 = cvt8(ld4(wrow + 32), ld4(wrow + 36));
        f32x4_t acc = {0.f, 0.f, 0.f, 0.f};
        acc = MFMA16(af0, bf0, acc);
        acc = MFMA16(af1, bf1, acc);
        // C layout: row(j_local) = q*4 + r, col(f_local) = m
        const int j0 = w * 16 + q * 4;
        bf16x4_t v;
        v[0] = (__bf16)acc[0]; v[1] = (__bf16)acc[1];
        v[2] = (__bf16)acc[2]; v[3] = (__bf16)acc[3];
        *reinterpret_cast<bf16x4_t*>(&T[f][j0]) = v;
    }
    __syncthreads();

    // Write 8-elem (16B) chunks; 1000 % 8 == 0 so no chunk straddles jj=1000.
    const size_t rowbase = (size_t)((b * 2 + h) * kD);
    #pragma unroll
    for (int rep = 0; rep < 2; ++rep) {
        const int cc = tid + rep * 256;       // 0..511
        const int f  = cc >> 3;
        const int ch = cc & 7;
        const int jj0 = jt * 64 + ch * 8;
        if (jj0 < kN) {
            const uint4 v = *reinterpret_cast<uint4*>(&T[f][ch * 8]);
            *reinterpret_cast<uint4*>(SWT + (rowbase + f) * kNE + e * kN + jj0) = v;
        }
    }
}

// ---------------------------------------------------------------------------
// a_half[b][i][f] = sum_j A[b][i][h*4000 + j] * SWT[(b*2+h)*64 + f][j]
// grid: 256 = 16 row-tiles x 2 h x 8 b; block 256 = 4 waves x (16 rows, 64 cols).
// Barrier-free K-loop: A f32 from HBM (cvt to bf16 in-register), B bf16
// direct from global (L1/L2 resident), depth-1 register prefetch.
// ---------------------------------------------------------------------------
__global__ __launch_bounds__(256) void big_mm(
    const float* __restrict__ A,        // [8][1000][8000]
    const __bf16* __restrict__ SWT,     // [16*64][4000]
    float* __restrict__ a_in,           // [8][1000][64]
    float* __restrict__ a_out)
{
    const int bx   = blockIdx.x;
    const int tile = bx & 15;
    const int h    = (bx >> 4) & 1;
    const int b    = bx >> 5;
    const int tid  = threadIdx.x;
    const int w    = tid >> 6;
    const int lane = tid & 63;
    const int m    = lane & 15;
    const int q    = lane >> 4;

    const int row  = tile * 64 + w * 16 + m;
    const int rowc = row < kN ? row : kN - 1;

    const float*  Ap = A + ((size_t)b * kN + rowc) * (2 * kNE) + h * kNE + q * 8;
    const __bf16* SW = SWT + ((size_t)(b * 2 + h) * kD) * kNE + q * 8;
    const __bf16* SB0 = SW + (size_t)(0 * 16 + m) * kNE;
    const __bf16* SB1 = SW + (size_t)(1 * 16 + m) * kNE;
    const __bf16* SB2 = SW + (size_t)(2 * 16 + m) * kNE;
    const __bf16* SB3 = SW + (size_t)(3 * 16 + m) * kNE;

    f32x4_t acc0 = {0.f, 0.f, 0.f, 0.f};
    f32x4_t acc1 = {0.f, 0.f, 0.f, 0.f};
    f32x4_t acc2 = {0.f, 0.f, 0.f, 0.f};
    f32x4_t acc3 = {0.f, 0.f, 0.f, 0.f};

    // prologue: k0 = 0 (both 32-halves)
    bf16x8_t ca0 = cvt8(ld4(Ap + 0),  ld4(Ap + 4));
    bf16x8_t ca1 = cvt8(ld4(Ap + 32), ld4(Ap + 36));
    bf16x8_t cb00 = *(const bf16x8_t*)(SB0);
    bf16x8_t cb01 = *(const bf16x8_t*)(SB1);
    bf16x8_t cb02 = *(const bf16x8_t*)(SB2);
    bf16x8_t cb03 = *(const bf16x8_t*)(SB3);
    bf16x8_t cb10 = *(const bf16x8_t*)(SB0 + 32);
    bf16x8_t cb11 = *(const bf16x8_t*)(SB1 + 32);
    bf16x8_t cb12 = *(const bf16x8_t*)(SB2 + 32);
    bf16x8_t cb13 = *(const bf16x8_t*)(SB3 + 32);

    // K = 4000 = 62*64 + 32 tail
    for (int kk = 0; kk < 62; ++kk) {
        const int kn = (kk + 1) * 64;
        // second-half prefetch of the last iteration would run past K=4000;
        // redirect it to offset 0 (valid, result unused by the tail).
        const int k2 = (kk < 61) ? (kn + 32) : 0;

        const float4 x0 = ld4(Ap + kn),  x1 = ld4(Ap + kn + 4);
        const float4 x2 = ld4(Ap + k2),  x3 = ld4(Ap + k2 + 4);
        const bf16x8_t nb00 = *(const bf16x8_t*)(SB0 + kn);
        const bf16x8_t nb01 = *(const bf16x8_t*)(SB1 + kn);
        const bf16x8_t nb02 = *(const bf16x8_t*)(SB2 + kn);
        const bf16x8_t nb03 = *(const bf16x8_t*)(SB3 + kn);
        const bf16x8_t nb10 = *(const bf16x8_t*)(SB0 + k2);
        const bf16x8_t nb11 = *(const bf16x8_t*)(SB1 + k2);
        const bf16x8_t nb12 = *(const bf16x8_t*)(SB2 + k2);
        const bf16x8_t nb13 = *(const bf16x8_t*)(SB3 + k2);

        acc0 = MFMA16(ca0, cb00, acc0);
        acc1 = MFMA16(ca0, cb01, acc1);
        acc2 = MFMA16(ca0, cb02, acc2);
        acc3 = MFMA16(ca0, cb03, acc3);
        acc0 = MFMA16(ca1, cb10, acc0);
        acc1 = MFMA16(ca1, cb11, acc1);
        acc2 = MFMA16(ca1, cb12, acc2);
        acc3 = MFMA16(ca1, cb13, acc3);

        ca0 = cvt8(x0, x1);
        ca1 = cvt8(x2, x3);
        cb00 = nb00; cb01 = nb01; cb02 = nb02; cb03 = nb03;
        cb10 = nb10; cb11 = nb11; cb12 = nb12; cb13 = nb13;
    }
    // tail: k0 = 3968, 32 wide (first half only)
    acc0 = MFMA16(ca0, cb00, acc0);
    acc1 = MFMA16(ca0, cb01, acc1);
    acc2 = MFMA16(ca0, cb02, acc2);
    acc3 = MFMA16(ca0, cb03, acc3);

    float* dst = (h ? a_out : a_in) + (size_t)b * kN * kD;
    const int i0 = tile * 64 + w * 16 + q * 4;
    #pragma unroll
    for (int r = 0; r < 4; ++r) {
        const int i = i0 + r;
        if (i < kN) {
            float* drow = dst + (size_t)i * kD + m;
            drow[0]  = acc0[r];
            drow[16] = acc1[r];
            drow[32] = acc2[r];
            drow[48] = acc3[r];
        }
    }
}

// ---------------------------------------------------------------------------
// Gating: per 16 rows (one wave, one block of 64):
//   a = [a_in | a_out | state] (K=192)
//   r = sigm(a @ W_r^T); z = sigm(a @ W_z^T)
//   h = tanh([a_in|a_out] @ W_h[:, :128]^T + (r*state) @ W_h[:, 128:]^T)
//   ns = (1-z)*state + z*h
// step 1: write ns to s_next. step 2: fused head:
//   out = sum_k tanh([ns|ann] @ Wo1^T)[k] * Wo2[k]
// ---------------------------------------------------------------------------
__global__ __launch_bounds__(64) void gating(
    const float* __restrict__ a_in,
    const float* __restrict__ a_out,
    const float* __restrict__ state,
    const float* __restrict__ W_r,
    const float* __restrict__ W_z,
    const float* __restrict__ W_h,
    float* __restrict__ s_next,
    const float* __restrict__ ann,
    const float* __restrict__ Wo1,
    const float* __restrict__ Wo2,
    float* __restrict__ out,
    const int step)
{
    const int i0   = blockIdx.x * 16;
    const int lane = threadIdx.x;
    const int m    = lane & 15;
    const int q    = lane >> 4;

    __shared__ __bf16 TL[16][72];  // wave-local C-layout -> A-layout transpose

    const size_t rowA = (size_t)(i0 + m);

    bf16x8_t xf[6];
    {
        const float* p = a_in + rowA * kD + q * 8;
        xf[0] = cvt8(ld4(p),      ld4(p + 4));
        xf[1] = cvt8(ld4(p + 32), ld4(p + 36));
        p = a_out + rowA * kD + q * 8;
        xf[2] = cvt8(ld4(p),      ld4(p + 4));
        xf[3] = cvt8(ld4(p + 32), ld4(p + 36));
        p = state + rowA * kD + q * 8;
        xf[4] = cvt8(ld4(p),      ld4(p + 4));
        xf[5] = cvt8(ld4(p + 32), ld4(p + 36));
    }

    f32x4_t accr[4], accz[4], acch[4];
    #pragma unroll
    for (int c = 0; c < 4; ++c) {
        accr[c] = {0.f, 0.f, 0.f, 0.f};
        accz[c] = {0.f, 0.f, 0.f, 0.f};
        acch[c] = {0.f, 0.f, 0.f, 0.f};
    }

    #pragma unroll
    for (int c = 0; c < 4; ++c) {
        const int f = c * 16 + m;
        const float* wr = W_r + f * 192 + q * 8;
        const float* wz = W_z + f * 192 + q * 8;
        const float* wh = W_h + f * 192 + q * 8;
        #pragma unroll
        for (int kc = 0; kc < 6; ++kc) {
            bf16x8_t bw;
            bw = cvt8(ld4(wr + kc * 32), ld4(wr + kc * 32 + 4));
            accr[c] = MFMA16(xf[kc], bw, accr[c]);
            bw = cvt8(ld4(wz + kc * 32), ld4(wz + kc * 32 + 4));
            accz[c] = MFMA16(xf[kc], bw, accz[c]);
            if (kc < 4) {  // h uses only [a_in|a_out] here (K=128)
                bw = cvt8(ld4(wh + kc * 32), ld4(wh + kc * 32 + 4));
                acch[c] = MFMA16(xf[kc], bw, acch[c]);
            }
        }
    }

    // state in C layout: row = q*4+r, col = c*16+m
    float sC[4][4];
    #pragma unroll
    for (int c = 0; c < 4; ++c)
        #pragma unroll
        for (int r = 0; r < 4; ++r)
            sC[c][r] = state[(size_t)(i0 + q * 4 + r) * kD + c * 16 + m];

    // rs = sigm(r_pre) * state, transposed to A layout through LDS
    #pragma unroll
    for (int c = 0; c < 4; ++c)
        #pragma unroll
        for (int r = 0; r < 4; ++r)
            TL[q * 4 + r][c * 16 + m] = (__bf16)(sigm(accr[c][r]) * sC[c][r]);
    __syncthreads();
    const bf16x8_t rs0 = *(const bf16x8_t*)&TL[m][q * 8];
    const bf16x8_t rs1 = *(const bf16x8_t*)&TL[m][32 + q * 8];

    #pragma unroll
    for (int c = 0; c < 4; ++c) {
        const int f = c * 16 + m;
        const float* wh3 = W_h + f * 192 + 128 + q * 8;
        acch[c] = MFMA16(rs0, cvt8(ld4(wh3),      ld4(wh3 + 4)),  acch[c]);
        acch[c] = MFMA16(rs1, cvt8(ld4(wh3 + 32), ld4(wh3 + 36)), acch[c]);
    }

    float ns[4][4];
    #pragma unroll
    for (int c = 0; c < 4; ++c)
        #pragma unroll
        for (int r = 0; r < 4; ++r) {
            const float zv = sigm(accz[c][r]);
            const float hv = fast_tanh(acch[c][r]);
            ns[c][r] = (1.f - zv) * sC[c][r] + zv * hv;
        }

    if (step == 1) {
        #pragma unroll
        for (int c = 0; c < 4; ++c)
            #pragma unroll
            for (int r = 0; r < 4; ++r)
                s_next[(size_t)(i0 + q * 4 + r) * kD + c * 16 + m] = ns[c][r];
    } else {
        __syncthreads();  // everyone done reading TL (rs frags)
        #pragma unroll
        for (int c = 0; c < 4; ++c)
            #pragma unroll
            for (int r = 0; r < 4; ++r)
                TL[q * 4 + r][c * 16 + m] = (__bf16)ns[c][r];
        __syncthreads();
        const bf16x8_t j0 = *(const bf16x8_t*)&TL[m][q * 8];
        const bf16x8_t j1 = *(const bf16x8_t*)&TL[m][32 + q * 8];
        const float* ap = ann + rowA * kAD + q * 8;
        const bf16x8_t j2 = cvt8(ld4(ap), ld4(ap + 4));

        f32x4_t acco[4];
        #pragma unroll
        for (int c = 0; c < 4; ++c) acco[c] = {0.f, 0.f, 0.f, 0.f};
        #pragma unroll
        for (int c = 0; c < 4; ++c) {
            const float* wo = Wo1 + (size_t)(c * 16 + m) * 96 + q * 8;
            acco[c] = MFMA16(j0, cvt8(ld4(wo),      ld4(wo + 4)),  acco[c]);
            acco[c] = MFMA16(j1, cvt8(ld4(wo + 32), ld4(wo + 36)), acco[c]);
            acco[c] = MFMA16(j2, cvt8(ld4(wo + 64), ld4(wo + 68)), acco[c]);
        }
        float vs[4] = {0.f, 0.f, 0.f, 0.f};
        #pragma unroll
        for (int c = 0; c < 4; ++c) {
            const float w2 = Wo2[c * 16 + m];
            #pragma unroll
            for (int r = 0; r < 4; ++r)
                vs[r] += fast_tanh(acco[c][r]) * w2;
        }
        // reduce over the 16 lanes (m) of each quad
        #pragma unroll
        for (int off = 1; off <= 8; off <<= 1) {
            #pragma unroll
            for (int r = 0; r < 4; ++r)
                vs[r] += __shfl_xor(vs[r], off, 64);
        }
        if (m == 0) {
            #pragma unroll
            for (int r = 0; r < 4; ++r)
                out[i0 + q * 4 + r] = vs[r];
        }
    }
}

extern "C" void kernel_launch(void* const* d_in, const int* in_sizes, int n_in,
                              void* d_out, int out_size, void* d_ws, size_t ws_size,
                              hipStream_t stream) {
    (void)in_sizes; (void)n_in; (void)out_size; (void)ws_size;

    const float* prop_state = (const float*)d_in[0];
    const float* annotation = (const float*)d_in[1];
    const float* A          = (const float*)d_in[2];
    const float* W_in       = (const float*)d_in[3];
    const float* W_out      = (const float*)d_in[4];
    const float* W_r        = (const float*)d_in[5];
    const float* W_z        = (const float*)d_in[6];
    const float* W_h        = (const float*)d_in[7];
    const float* Wo1        = (const float*)d_in[8];
    const float* Wo2        = (const float*)d_in[9];
    float* out = (float*)d_out;

    char* ws = (char*)d_ws;
    __bf16* SWT  = (__bf16*)(ws);                 // 8*2*64*4000*2  = 8,192,000 B
    float*  a_in = (float*)(ws + 8192000);        // 8000*64*4      = 2,048,000 B
    float*  a_out= (float*)(ws + 10240000);       // 2,048,000 B
    float*  s1   = (float*)(ws + 12288000);       // 2,048,000 B  (total 14.3 MB)

    // step 1
    precompute_swt<<<1024, 256, 0, stream>>>(prop_state, W_in, W_out, SWT);
    big_mm<<<256, 256, 0, stream>>>(A, SWT, a_in, a_out);
    gating<<<500, 64, 0, stream>>>(a_in, a_out, prop_state, W_r, W_z, W_h,
                                   s1, nullptr, nullptr, nullptr, nullptr, 1);
    // step 2 (+ fused output head)
    precompute_swt<<<1024, 256, 0, stream>>>(s1, W_in, W_out, SWT);
    big_mm<<<256, 256, 0, stream>>>(A, SWT, a_in, a_out);
    gating<<<500, 64, 0, stream>>>(a_in, a_out, s1, W_r, W_z, W_h,
                                   nullptr, annotation, Wo1, Wo2, out, 2);
}